// Round 1
// baseline (298.954 us; speedup 1.0000x reference)
//
#include <hip/hip_runtime.h>
#include <hip/hip_bf16.h>
#include <math.h>

namespace {

typedef unsigned short u16;
typedef unsigned int u32;

constexpr int LSEQ = 22, CD = 128, DI = 256, TDIM = 64;

// LDS strides (u16 units unless noted)
constexpr int XS_LD = 136;
constexpr int XI_LD = 264;
constexpr int Y2_LD = 132;   // f32

// ---- K1 LDS pool (u16 offsets) ----
//   xs [0,2992) overlays dt f32[22][8] (352 u16) + bc f32[22][32] (1408 u16)
//   (xs dead after P1; dt/bc written in P3)
constexpr int K1_XS = 0;
constexpr int K1_XI = 2992;    // 22x264 bf16 (xi -> xc -> consumed)
constexpr int K1_Z  = 8800;    // 22x264 bf16
constexpr int K1_N  = 14608;   // 29216 B -> 5 blocks/CU

// ---- K2 LDS pool ----
//   yf [0,5808), yb [5808,11616); y2 f32[22][132] overlays yf after MFMA;
//   mu/rs overlay yb start.
constexpr int K2_N  = 11616;   // 23232 B -> 6 blocks/CU

// ws segments (u16 element offsets)
constexpr int WS_F_IN_HI = 0;        // 512x128
constexpr int WS_F_IN_LO = 65536;
constexpr int WS_B_IN_HI = 131072;
constexpr int WS_B_IN_LO = 196608;
constexpr int WS_F_OUT   = 262144;   // 128x256: prep_fold -> Wf = fuse[:, :128] @ f_out_w
constexpr int WS_B_OUT   = 294912;   // 128x256: prep_fold -> Wb = fuse[:, 128:] @ b_out_w
constexpr int WS_FUSE    = 327680;   // dead after fold
constexpr int WS_F_XP_HI = 360448;   // 48x256 (rows 40..47 zero)
constexpr int WS_F_XP_LO = 372736;
constexpr int WS_B_XP_HI = 385024;
constexpr int WS_B_XP_LO = 397312;
constexpr int WS_TOTAL   = 409600;   // 800 KiB
// y staging: per (nm,t): 2 dirs x 22 x 256 bf16 = 11264 u16. bwd stored
// pre-un-reversed (row = sequence position). Total 2048*11264 u16 = 44 MiB.
constexpr int WS_Y       = 409600;

typedef __attribute__((ext_vector_type(8))) short bf16x8;
typedef __attribute__((ext_vector_type(4))) float f32x4;

__device__ __forceinline__ u16 f2bf(float f) {
  __bf16 b = (__bf16)f;
  return *reinterpret_cast<u16*>(&b);
}
__device__ __forceinline__ float bf2f(u16 h) {
  return __uint_as_float(((u32)h) << 16);
}
__device__ __forceinline__ float sigm(float x) { return 1.0f / (1.0f + __expf(-x)); }

__global__ void prep_weights(const float* __restrict__ f_in, const float* __restrict__ b_in,
                             const float* __restrict__ f_xp, const float* __restrict__ b_xp,
                             u16* __restrict__ ws) {
  int i = blockIdx.x * 256 + threadIdx.x;
  if (i >= WS_TOTAL) return;
  u16 r = 0;
  if (i < WS_F_IN_LO) {
    r = f2bf(f_in[i]);
  } else if (i < WS_B_IN_HI) {
    float v = f_in[i - WS_F_IN_LO];
    r = f2bf(v - bf2f(f2bf(v)));
  } else if (i < WS_B_IN_LO) {
    r = f2bf(b_in[i - WS_B_IN_HI]);
  } else if (i < WS_F_OUT) {
    float v = b_in[i - WS_B_IN_LO];
    r = f2bf(v - bf2f(f2bf(v)));
  } else if (i < WS_F_XP_HI) {
    r = 0;  // OUT slots: filled by prep_fold; FUSE dead
  } else if (i < WS_F_XP_LO) {
    int j = i - WS_F_XP_HI, n = j >> 8, k = j & 255;
    r = (n < 40) ? f2bf(f_xp[n * 256 + k]) : (u16)0;
  } else if (i < WS_B_XP_HI) {
    int j = i - WS_F_XP_LO, n = j >> 8, k = j & 255;
    if (n < 40) { float v = f_xp[n * 256 + k]; r = f2bf(v - bf2f(f2bf(v))); } else r = 0;
  } else if (i < WS_B_XP_LO) {
    int j = i - WS_B_XP_HI, n = j >> 8, k = j & 255;
    r = (n < 40) ? f2bf(b_xp[n * 256 + k]) : (u16)0;
  } else {
    int j = i - WS_B_XP_LO, n = j >> 8, k = j & 255;
    if (n < 40) { float v = b_xp[n * 256 + k]; r = f2bf(v - bf2f(f2bf(v))); } else r = 0;
  }
  ws[i] = r;
}

// Wf = fuse_w[:, :128] @ f_out_w ; Wb = fuse_w[:, 128:] @ b_out_w  (each 128x256)
__global__ void prep_fold(const float* __restrict__ f_out, const float* __restrict__ b_out,
                          const float* __restrict__ fuse, u16* __restrict__ ws) {
  int i = blockIdx.x * 256 + threadIdx.x;   // 65536 outputs
  int half = i >> 15;
  int j = i & 32767;
  int c = j >> 8, d = j & 255;
  const float* ow = half ? b_out : f_out;
  const float* fw = fuse + c * 256 + half * 128;
  float acc = 0.f;
#pragma unroll 4
  for (int k = 0; k < 128; ++k) acc = fmaf(fw[k], ow[k * 256 + d], acc);
  ws[(half ? WS_B_OUT : WS_F_OUT) + c * 256 + d] = f2bf(acc);
}

// ============ K1: per (nm, t, dir) — in_proj, conv, x_proj, scan ============
__global__ __launch_bounds__(256, 5) void mamba_scan_kernel(
    const float* __restrict__ x,
    const float* __restrict__ f_conv_w, const float* __restrict__ f_conv_b,
    const float* __restrict__ f_dt_w, const float* __restrict__ f_dt_b,
    const float* __restrict__ f_Alog, const float* __restrict__ f_D,
    const float* __restrict__ b_conv_w, const float* __restrict__ b_conv_b,
    const float* __restrict__ b_dt_w, const float* __restrict__ b_dt_b,
    const float* __restrict__ b_Alog, const float* __restrict__ b_D,
    u16* __restrict__ ws)
{
  __shared__ __align__(16) u16 pool[K1_N];

  u16* xs  = pool + K1_XS;
  u16* xiD = pool + K1_XI;
  u16* zD  = pool + K1_Z;

  const int tid = threadIdx.x;
  const int wv = tid >> 6, ln = tid & 63, lr = ln & 15, lg = ln >> 4;
  const int bid = blockIdx.x;
  const int b = bid >> 1, dir = bid & 1;
  const int nm = b / TDIM, t = b - nm * TDIM;
  const size_t base = (size_t)nm * CD * (TDIM * LSEQ) + (size_t)t * LSEQ;

  const int ra0 = (lr < LSEQ) ? lr : (LSEQ - 1);
  const int ra1 = (16 + lr < LSEQ) ? (16 + lr) : (LSEQ - 1);

  // ---- stage xs (bf16) ----
  for (int idx = tid; idx < LSEQ * CD; idx += 256) {
    int c = idx / LSEQ, v = idx - c * LSEQ;
    xs[v * XS_LD + c] = f2bf(x[base + (size_t)c * (TDIM * LSEQ) + v]);
  }
  __syncthreads();

  // ---- P1: in_proj MFMA (one dir). Wave wv owns 128 output cols. ----
  {
    bf16x8 afr[2][4];
#pragma unroll
    for (int kt = 0; kt < 4; ++kt) {
      afr[0][kt] = *(const bf16x8*)&xs[ra0 * XS_LD + kt * 32 + lg * 8];
      afr[1][kt] = *(const bf16x8*)&xs[ra1 * XS_LD + kt * 32 + lg * 8];
    }
    const u16* ih = ws + (dir ? WS_B_IN_HI : WS_F_IN_HI);
    const u16* il = ws + (dir ? WS_B_IN_LO : WS_F_IN_LO);
    u16* dst = (wv < 2) ? xiD : zD;       // cols 0..255 -> xi, 256..511 -> z
    const int cb0 = (wv & 1) * 128;
#pragma unroll
    for (int half = 0; half < 2; ++half) {   // two 64-col sub-tiles to cap VGPRs
      f32x4 acc[2][4];
#pragma unroll
      for (int m = 0; m < 2; ++m)
#pragma unroll
        for (int n = 0; n < 4; ++n) acc[m][n] = f32x4{0.f, 0.f, 0.f, 0.f};
#pragma unroll
      for (int kt = 0; kt < 4; ++kt) {
#pragma unroll
        for (int n = 0; n < 4; ++n) {
          const int off = (wv * 128 + (half * 4 + n) * 16 + lr) * 128 + kt * 32 + lg * 8;
          bf16x8 bh = *(const bf16x8*)(ih + off);
          bf16x8 bl = *(const bf16x8*)(il + off);
          acc[0][n] = __builtin_amdgcn_mfma_f32_16x16x32_bf16(afr[0][kt], bh, acc[0][n], 0, 0, 0);
          acc[0][n] = __builtin_amdgcn_mfma_f32_16x16x32_bf16(afr[0][kt], bl, acc[0][n], 0, 0, 0);
          acc[1][n] = __builtin_amdgcn_mfma_f32_16x16x32_bf16(afr[1][kt], bh, acc[1][n], 0, 0, 0);
          acc[1][n] = __builtin_amdgcn_mfma_f32_16x16x32_bf16(afr[1][kt], bl, acc[1][n], 0, 0, 0);
        }
      }
#pragma unroll
      for (int m = 0; m < 2; ++m)
#pragma unroll
        for (int n = 0; n < 4; ++n)
#pragma unroll
          for (int j = 0; j < 4; ++j) {
            int row = 16 * m + lg * 4 + j;
            if (row < LSEQ) {
              int rr = dir ? (LSEQ - 1 - row) : row;    // bwd: store reversed
              dst[rr * XI_LD + cb0 + half * 64 + n * 16 + lr] = f2bf(acc[m][n][j]);
            }
          }
    }
  }
  __syncthreads();

  // ---- P2: causal depthwise conv + SiLU, in-place, 1-ahead LDS prefetch ----
  {
    const int d = tid;
    const float* cw  = dir ? b_conv_w : f_conv_w;
    const float* cbp = dir ? b_conv_b : f_conv_b;
    float4 w4 = *(const float4*)(cw + d * 4);
    float bb = cbp[d];
    float w0 = 0.f, w1 = 0.f, w2 = 0.f;
    float nxt = bf2f(xiD[d]);            // l = 0
#pragma unroll
    for (int l = 0; l < LSEQ; ++l) {
      float w3 = nxt;
      if (l + 1 < LSEQ) nxt = bf2f(xiD[(l + 1) * XI_LD + d]);   // prefetch before write
      float a = fmaf(w0, w4.x, bb);
      a = fmaf(w1, w4.y, a);
      a = fmaf(w2, w4.z, a);
      a = fmaf(w3, w4.w, a);
      float s = a * sigm(a);
      xiD[l * XI_LD + d] = f2bf(s);      // xc overwrites xi
      w0 = w1; w1 = w2; w2 = w3;
    }
  }
  __syncthreads();

  // ---- P3: x_proj MFMA (6 wave-tiles over 4 waves) -> dt/bc f32 in LDS ----
  for (int tt = wv; tt < 6; tt += 4) {
    const int mt = tt / 3, nt = tt - mt * 3;
    const u16* xph = ws + (dir ? WS_B_XP_HI : WS_F_XP_HI);
    const u16* xpl = ws + (dir ? WS_B_XP_LO : WS_F_XP_LO);
    const int raa = (mt * 16 + lr < LSEQ) ? (mt * 16 + lr) : (LSEQ - 1);
    f32x4 acc = f32x4{0.f, 0.f, 0.f, 0.f};
    const u16* bh_p = xph + (nt * 16 + lr) * 256 + lg * 8;
    const u16* bl_p = xpl + (nt * 16 + lr) * 256 + lg * 8;
#pragma unroll
    for (int kt = 0; kt < 8; ++kt) {
      bf16x8 a  = *(const bf16x8*)&xiD[raa * XI_LD + kt * 32 + lg * 8];
      bf16x8 bh = *(const bf16x8*)(bh_p + kt * 32);
      bf16x8 bl = *(const bf16x8*)(bl_p + kt * 32);
      acc = __builtin_amdgcn_mfma_f32_16x16x32_bf16(a, bh, acc, 0, 0, 0);
      acc = __builtin_amdgcn_mfma_f32_16x16x32_bf16(a, bl, acc, 0, 0, 0);
    }
    const int col = nt * 16 + lr;
    float* dtD = (float*)pool;           // f32[22][8]  at u16 offset 0
    float* bcD = ((float*)pool) + 176;   // f32[22][32] at u16 offset 352
#pragma unroll
    for (int j = 0; j < 4; ++j) {
      int row = mt * 16 + lg * 4 + j;
      if (row < LSEQ) {
        if (col < 8) dtD[row * 8 + col] = acc[j];
        else if (col < 40) bcD[row * 32 + (col - 8)] = acc[j];
      }
    }
  }
  __syncthreads();

  // ---- P4: softplus(dt) pipelined + selective scan + D-skip + SiLU gate ----
  {
    const int d = tid;
    const float* dtw  = dir ? b_dt_w : f_dt_w;
    const float* dtb  = dir ? b_dt_b : f_dt_b;
    const float* Alog = dir ? b_Alog : f_Alog;
    const float* Dp   = dir ? b_D : f_D;
    const float* dtD  = (const float*)pool;
    const float* bcD  = ((const float*)pool) + 176;

    float4 dw0 = *(const float4*)(dtw + d * 8);
    float4 dw1 = *(const float4*)(dtw + d * 8 + 4);
    const float dtbv = dtb[d];
    float Av[16];
#pragma unroll
    for (int s4 = 0; s4 < 4; ++s4) {
      float4 a = *(const float4*)(Alog + d * 16 + s4 * 4);
      Av[s4 * 4 + 0] = -__expf(a.x);
      Av[s4 * 4 + 1] = -__expf(a.y);
      Av[s4 * 4 + 2] = -__expf(a.z);
      Av[s4 * 4 + 3] = -__expf(a.w);
    }
    const float Dd = Dp[d];
    u16* wsY = ws + WS_Y + (size_t)b * 11264 + dir * 5632;

    auto softp = [&](int l) -> float {
      float4 q0 = *(const float4*)(dtD + l * 8);
      float4 q1 = *(const float4*)(dtD + l * 8 + 4);
      float sdt = dtbv;
      sdt = fmaf(q0.x, dw0.x, sdt); sdt = fmaf(q0.y, dw0.y, sdt);
      sdt = fmaf(q0.z, dw0.z, sdt); sdt = fmaf(q0.w, dw0.w, sdt);
      sdt = fmaf(q1.x, dw1.x, sdt); sdt = fmaf(q1.y, dw1.y, sdt);
      sdt = fmaf(q1.z, dw1.z, sdt); sdt = fmaf(q1.w, dw1.w, sdt);
      return (sdt > 20.f) ? sdt : __logf(1.f + __expf(sdt));
    };

    float h[16];
#pragma unroll
    for (int s = 0; s < 16; ++s) h[s] = 0.f;
    float dtv = softp(0);
    for (int l = 0; l < LSEQ; ++l) {
      // next step's dt off the loop-carried chain
      float dtv_n = (l + 1 < LSEQ) ? softp(l + 1) : 0.f;
      float u = bf2f(xiD[l * XI_LD + d]);   // xc
      float du = dtv * u;
      float4 b0 = *(const float4*)(bcD + l * 32);
      float4 b1 = *(const float4*)(bcD + l * 32 + 4);
      float4 b2 = *(const float4*)(bcD + l * 32 + 8);
      float4 b3 = *(const float4*)(bcD + l * 32 + 12);
      float4 c0 = *(const float4*)(bcD + l * 32 + 16);
      float4 c1 = *(const float4*)(bcD + l * 32 + 20);
      float4 c2 = *(const float4*)(bcD + l * 32 + 24);
      float4 c3 = *(const float4*)(bcD + l * 32 + 28);
      float acc = 0.f;
#define SC(s, bv, cv) { float dA = __expf(dtv * Av[s]); \
      h[s] = fmaf(dA, h[s], du * (bv)); \
      acc = fmaf(h[s], (cv), acc); }
      SC(0, b0.x, c0.x) SC(1, b0.y, c0.y) SC(2, b0.z, c0.z) SC(3, b0.w, c0.w)
      SC(4, b1.x, c1.x) SC(5, b1.y, c1.y) SC(6, b1.z, c1.z) SC(7, b1.w, c1.w)
      SC(8, b2.x, c2.x) SC(9, b2.y, c2.y) SC(10, b2.z, c2.z) SC(11, b2.w, c2.w)
      SC(12, b3.x, c3.x) SC(13, b3.y, c3.y) SC(14, b3.z, c3.z) SC(15, b3.w, c3.w)
#undef SC
      float zv = bf2f(zD[l * XI_LD + d]);
      float yo = fmaf(u, Dd, acc) * zv * sigm(zv);
      // bwd scan iter l is sequence position 21-l: store un-reversed
      wsY[(dir ? (LSEQ - 1 - l) : l) * DI + d] = f2bf(yo);
      dtv = dtv_n;
    }
  }
}

// ============ K2: per (nm, t) — folded out_proj/fuse + LayerNorm ============
__global__ __launch_bounds__(256, 6) void fold_ln_kernel(
    const float* __restrict__ ln_w, const float* __restrict__ ln_b,
    const u16* __restrict__ ws, float* __restrict__ out)
{
  __shared__ __align__(16) u16 pool[K2_N];

  const int tid = threadIdx.x;
  const int wv = tid >> 6, ln = tid & 63, lr = ln & 15, lg = ln >> 4;
  const int b = blockIdx.x;
  const int nm = b / TDIM, t = b - nm * TDIM;
  const size_t base = (size_t)nm * CD * (TDIM * LSEQ) + (size_t)t * LSEQ;
  const u16* wsY = ws + WS_Y + (size_t)b * 11264;

  // ---- stage y_f, y_b (both already in sequence order) ----
  for (int idx = tid; idx < 2 * LSEQ * 32; idx += 256) {   // 1408 x bf16x8
    int dirc = idx / 704, r = idx - dirc * 704;
    int l = r >> 5, ch = (r & 31) * 8;
    *(bf16x8*)&pool[dirc * 5808 + l * XI_LD + ch] =
        *(const bf16x8*)(wsY + dirc * 5632 + l * 256 + ch);
  }
  __syncthreads();

  const int ra0 = (lr < LSEQ) ? lr : (LSEQ - 1);
  const int ra1 = (16 + lr < LSEQ) ? (16 + lr) : (LSEQ - 1);

  // ---- y2 = y_f @ Wf.T + y_b @ Wb.T ----
  f32x4 acc[2][2];
#pragma unroll
  for (int m = 0; m < 2; ++m)
#pragma unroll
    for (int n = 0; n < 2; ++n) acc[m][n] = f32x4{0.f, 0.f, 0.f, 0.f};
#pragma unroll
  for (int dirc = 0; dirc < 2; ++dirc) {
    const u16* wp = ws + (dirc ? WS_B_OUT : WS_F_OUT);
    const u16* yD = pool + dirc * 5808;
#pragma unroll
    for (int kt = 0; kt < 8; ++kt) {
      bf16x8 a0 = *(const bf16x8*)&yD[ra0 * XI_LD + kt * 32 + lg * 8];
      bf16x8 a1 = *(const bf16x8*)&yD[ra1 * XI_LD + kt * 32 + lg * 8];
#pragma unroll
      for (int n = 0; n < 2; ++n) {
        bf16x8 bw = *(const bf16x8*)(wp + (wv * 32 + n * 16 + lr) * 256 + kt * 32 + lg * 8);
        acc[0][n] = __builtin_amdgcn_mfma_f32_16x16x32_bf16(a0, bw, acc[0][n], 0, 0, 0);
        acc[1][n] = __builtin_amdgcn_mfma_f32_16x16x32_bf16(a1, bw, acc[1][n], 0, 0, 0);
      }
    }
  }
  __syncthreads();   // all waves done reading yf/yb before overlay write

  float* y2 = (float*)pool;   // [22][132], overlays yf
#pragma unroll
  for (int m = 0; m < 2; ++m)
#pragma unroll
    for (int n = 0; n < 2; ++n)
#pragma unroll
      for (int j = 0; j < 4; ++j) {
        int row = 16 * m + lg * 4 + j;
        if (row < LSEQ) y2[row * Y2_LD + wv * 32 + n * 16 + lr] = acc[m][n][j];
      }
  __syncthreads();

  // ---- LayerNorm stats (one wave per row) ----
  float* mu_s = (float*)(pool + 5808);   // overlays yb
  float* rs_s = mu_s + LSEQ;
  for (int l = wv; l < LSEQ; l += 4) {
    float v1 = y2[l * Y2_LD + ln];
    float v2 = y2[l * Y2_LD + 64 + ln];
    float s = v1 + v2;
    float sq = v1 * v1 + v2 * v2;
#pragma unroll
    for (int m = 1; m < 64; m <<= 1) {
      s  += __shfl_xor(s, m, 64);
      sq += __shfl_xor(sq, m, 64);
    }
    if (ln == 0) {
      float mu = s * (1.0f / 128.0f);
      float var = sq * (1.0f / 128.0f) - mu * mu;
      mu_s[l] = mu;
      rs_s[l] = rsqrtf(var + 1e-5f);
    }
  }
  __syncthreads();

  // ---- normalize + transposed store ----
  for (int idx = tid; idx < LSEQ * CD; idx += 256) {
    int c = idx / LSEQ, v = idx - c * LSEQ;
    float yv = y2[v * Y2_LD + c];
    float o = (yv - mu_s[v]) * rs_s[v] * ln_w[c] + ln_b[c];
    out[base + (size_t)c * (TDIM * LSEQ) + v] = o;
  }
}

}  // namespace

extern "C" void kernel_launch(void* const* d_in, const int* in_sizes, int n_in,
                              void* d_out, int out_size, void* d_ws, size_t ws_size,
                              hipStream_t stream) {
  (void)in_sizes; (void)n_in; (void)ws_size; (void)out_size;
  const float* p[22];
  for (int i = 0; i < 22; ++i) p[i] = (const float*)d_in[i];
  u16* ws = (u16*)d_ws;
  prep_weights<<<dim3((WS_TOTAL + 255) / 256), dim3(256), 0, stream>>>(
      p[1], p[10], p[4], p[13], ws);
  prep_fold<<<dim3(256), dim3(256), 0, stream>>>(p[9], p[18], p[19], ws);
  mamba_scan_kernel<<<dim3(32 * 64 * 2), dim3(256), 0, stream>>>(
      p[0],
      p[2], p[3], p[5], p[6], p[7], p[8],
      p[11], p[12], p[14], p[15], p[16], p[17],
      ws);
  fold_ln_kernel<<<dim3(32 * 64), dim3(256), 0, stream>>>(
      p[20], p[21], ws, (float*)d_out);
}

// Round 2
// 289.435 us; speedup vs baseline: 1.0329x; 1.0329x over previous
//
#include <hip/hip_runtime.h>
#include <hip/hip_bf16.h>
#include <math.h>

namespace {

typedef unsigned short u16;
typedef unsigned int u32;

constexpr int LSEQ = 22, CD = 128, DI = 256, TDIM = 64;

// LDS strides (u16 units unless noted)
constexpr int XS_LD = 136;
constexpr int XI_LD = 264;
constexpr int Y2_LD = 132;   // f32

// ---- K1 LDS pool (u16 offsets) ----
//   xs [0,2992) overlays dt f32[22][8] (352 u16) + bc f32[22][32] (1408 u16)
//   (xs dead after P1; dt/bc written in P3)
constexpr int K1_XS = 0;
constexpr int K1_XI = 2992;    // 22x264 bf16 (xi -> xc -> consumed)
constexpr int K1_Z  = 8800;    // 22x264 bf16 (holds g = silu(z) after P1)
constexpr int K1_N  = 14608;   // 29216 B -> 5 blocks/CU

// ---- K2 LDS pool ----
constexpr int K2_N  = 11616;   // 23232 B -> 6 blocks/CU

// ws segments (u16 element offsets)
constexpr int WS_F_IN_HI = 0;        // 512x128
constexpr int WS_F_IN_LO = 65536;
constexpr int WS_B_IN_HI = 131072;
constexpr int WS_B_IN_LO = 196608;
constexpr int WS_F_OUT   = 262144;   // 128x256: prep_fold -> Wf = fuse[:, :128] @ f_out_w
constexpr int WS_B_OUT   = 294912;   // 128x256: prep_fold -> Wb = fuse[:, 128:] @ b_out_w
constexpr int WS_FUSE    = 327680;   // dead after fold
constexpr int WS_F_XP_HI = 360448;   // 48x256 (rows 40..47 zero)
constexpr int WS_F_XP_LO = 372736;
constexpr int WS_B_XP_HI = 385024;
constexpr int WS_B_XP_LO = 397312;
constexpr int WS_TOTAL   = 409600;   // 800 KiB
// y staging: per (nm,t): 2 dirs x 22 x 256 bf16 = 11264 u16; bwd pre-un-reversed.
constexpr int WS_Y       = 409600;

typedef __attribute__((ext_vector_type(8))) short bf16x8;
typedef __attribute__((ext_vector_type(4))) float f32x4;

__device__ __forceinline__ u16 f2bf(float f) {
  __bf16 b = (__bf16)f;
  return *reinterpret_cast<u16*>(&b);
}
__device__ __forceinline__ float bf2f(u16 h) {
  return __uint_as_float(((u32)h) << 16);
}
// sigmoid without the IEEE-div sequence: 1/(1+exp(-x)) via v_exp + v_rcp
__device__ __forceinline__ float sigm(float x) {
  float e = __builtin_amdgcn_exp2f(-1.44269504f * x);
  return __builtin_amdgcn_rcpf(1.0f + e);
}

__global__ void prep_weights(const float* __restrict__ f_in, const float* __restrict__ b_in,
                             const float* __restrict__ f_xp, const float* __restrict__ b_xp,
                             u16* __restrict__ ws) {
  int i = blockIdx.x * 256 + threadIdx.x;
  if (i >= WS_TOTAL) return;
  u16 r = 0;
  if (i < WS_F_IN_LO) {
    r = f2bf(f_in[i]);
  } else if (i < WS_B_IN_HI) {
    float v = f_in[i - WS_F_IN_LO];
    r = f2bf(v - bf2f(f2bf(v)));
  } else if (i < WS_B_IN_LO) {
    r = f2bf(b_in[i - WS_B_IN_HI]);
  } else if (i < WS_F_OUT) {
    float v = b_in[i - WS_B_IN_LO];
    r = f2bf(v - bf2f(f2bf(v)));
  } else if (i < WS_F_XP_HI) {
    r = 0;  // OUT slots: filled by prep_fold; FUSE dead
  } else if (i < WS_F_XP_LO) {
    int j = i - WS_F_XP_HI, n = j >> 8, k = j & 255;
    r = (n < 40) ? f2bf(f_xp[n * 256 + k]) : (u16)0;
  } else if (i < WS_B_XP_HI) {
    int j = i - WS_F_XP_LO, n = j >> 8, k = j & 255;
    if (n < 40) { float v = f_xp[n * 256 + k]; r = f2bf(v - bf2f(f2bf(v))); } else r = 0;
  } else if (i < WS_B_XP_LO) {
    int j = i - WS_B_XP_HI, n = j >> 8, k = j & 255;
    r = (n < 40) ? f2bf(b_xp[n * 256 + k]) : (u16)0;
  } else {
    int j = i - WS_B_XP_LO, n = j >> 8, k = j & 255;
    if (n < 40) { float v = b_xp[n * 256 + k]; r = f2bf(v - bf2f(f2bf(v))); } else r = 0;
  }
  ws[i] = r;
}

// Wf = fuse_w[:, :128] @ f_out_w ; Wb = fuse_w[:, 128:] @ b_out_w  (each 128x256)
__global__ void prep_fold(const float* __restrict__ f_out, const float* __restrict__ b_out,
                          const float* __restrict__ fuse, u16* __restrict__ ws) {
  int i = blockIdx.x * 256 + threadIdx.x;   // 65536 outputs
  int half = i >> 15;
  int j = i & 32767;
  int c = j >> 8, d = j & 255;
  const float* ow = half ? b_out : f_out;
  const float* fw = fuse + c * 256 + half * 128;
  float acc = 0.f;
#pragma unroll 4
  for (int k = 0; k < 128; ++k) acc = fmaf(fw[k], ow[k * 256 + d], acc);
  ws[(half ? WS_B_OUT : WS_F_OUT) + c * 256 + d] = f2bf(acc);
}

// ============ K1: per (nm, t, dir) — in_proj, conv, x_proj, scan ============
__global__ __launch_bounds__(256, 5) void mamba_scan_kernel(
    const float* __restrict__ x,
    const float* __restrict__ f_conv_w, const float* __restrict__ f_conv_b,
    const float* __restrict__ f_dt_w, const float* __restrict__ f_dt_b,
    const float* __restrict__ f_Alog, const float* __restrict__ f_D,
    const float* __restrict__ b_conv_w, const float* __restrict__ b_conv_b,
    const float* __restrict__ b_dt_w, const float* __restrict__ b_dt_b,
    const float* __restrict__ b_Alog, const float* __restrict__ b_D,
    u16* __restrict__ ws)
{
  __shared__ __align__(16) u16 pool[K1_N];

  u16* xs  = pool + K1_XS;
  u16* xiD = pool + K1_XI;
  u16* zD  = pool + K1_Z;

  const int tid = threadIdx.x;
  const int wv = tid >> 6, ln = tid & 63, lr = ln & 15, lg = ln >> 4;
  const int bid = blockIdx.x;
  const int b = bid >> 1, dir = bid & 1;
  const int nm = b / TDIM, t = b - nm * TDIM;
  const size_t base = (size_t)nm * CD * (TDIM * LSEQ) + (size_t)t * LSEQ;

  const int ra0 = (lr < LSEQ) ? lr : (LSEQ - 1);
  const int ra1 = (16 + lr < LSEQ) ? (16 + lr) : (LSEQ - 1);

  // ---- stage xs (bf16) ----
#pragma unroll
  for (int k = 0; k < 11; ++k) {
    int idx = tid + k * 256;
    int c = idx / LSEQ, v = idx - c * LSEQ;
    xs[v * XS_LD + c] = f2bf(x[base + (size_t)c * (TDIM * LSEQ) + v]);
  }
  __syncthreads();

  // ---- P1: in_proj MFMA (one dir). Wave wv owns 128 output cols. ----
  {
    bf16x8 afr[2][4];
#pragma unroll
    for (int kt = 0; kt < 4; ++kt) {
      afr[0][kt] = *(const bf16x8*)&xs[ra0 * XS_LD + kt * 32 + lg * 8];
      afr[1][kt] = *(const bf16x8*)&xs[ra1 * XS_LD + kt * 32 + lg * 8];
    }
    const u16* ih = ws + (dir ? WS_B_IN_HI : WS_F_IN_HI);
    const u16* il = ws + (dir ? WS_B_IN_LO : WS_F_IN_LO);
    u16* dst = (wv < 2) ? xiD : zD;       // cols 0..255 -> xi, 256..511 -> z
    const bool isz = (wv >= 2);
    const int cb0 = (wv & 1) * 128;
#pragma unroll
    for (int half = 0; half < 2; ++half) {   // two 64-col sub-tiles to cap VGPRs
      f32x4 acc[2][4];
#pragma unroll
      for (int m = 0; m < 2; ++m)
#pragma unroll
        for (int n = 0; n < 4; ++n) acc[m][n] = f32x4{0.f, 0.f, 0.f, 0.f};
#pragma unroll
      for (int kt = 0; kt < 4; ++kt) {
        bf16x8 bh[4], bl[4];
#pragma unroll
        for (int n = 0; n < 4; ++n) {      // 8 loads in flight before MFMAs
          const int off = (wv * 128 + (half * 4 + n) * 16 + lr) * 128 + kt * 32 + lg * 8;
          bh[n] = *(const bf16x8*)(ih + off);
          bl[n] = *(const bf16x8*)(il + off);
        }
#pragma unroll
        for (int n = 0; n < 4; ++n) {
          acc[0][n] = __builtin_amdgcn_mfma_f32_16x16x32_bf16(afr[0][kt], bh[n], acc[0][n], 0, 0, 0);
          acc[0][n] = __builtin_amdgcn_mfma_f32_16x16x32_bf16(afr[0][kt], bl[n], acc[0][n], 0, 0, 0);
          acc[1][n] = __builtin_amdgcn_mfma_f32_16x16x32_bf16(afr[1][kt], bh[n], acc[1][n], 0, 0, 0);
          acc[1][n] = __builtin_amdgcn_mfma_f32_16x16x32_bf16(afr[1][kt], bl[n], acc[1][n], 0, 0, 0);
        }
      }
#pragma unroll
      for (int m = 0; m < 2; ++m)
#pragma unroll
        for (int n = 0; n < 4; ++n)
#pragma unroll
          for (int j = 0; j < 4; ++j) {
            int row = 16 * m + lg * 4 + j;
            if (row < LSEQ) {
              int rr = dir ? (LSEQ - 1 - row) : row;    // bwd: store reversed
              float v = acc[m][n][j];
              if (isz) v = v * sigm(v) * 1.0f, v = acc[m][n][j] * sigm(acc[m][n][j]);  // g = silu(z)
              dst[rr * XI_LD + cb0 + half * 64 + n * 16 + lr] = f2bf(v);
            }
          }
    }
  }
  __syncthreads();

  // ---- P2: causal depthwise conv + SiLU, in-place, 1-ahead LDS prefetch ----
  {
    const int d = tid;
    const float* cw  = dir ? b_conv_w : f_conv_w;
    const float* cbp = dir ? b_conv_b : f_conv_b;
    float4 w4 = *(const float4*)(cw + d * 4);
    float bb = cbp[d];
    float w0 = 0.f, w1 = 0.f, w2 = 0.f;
    float nxt = bf2f(xiD[d]);            // l = 0
#pragma unroll
    for (int l = 0; l < LSEQ; ++l) {
      float w3 = nxt;
      if (l + 1 < LSEQ) nxt = bf2f(xiD[(l + 1) * XI_LD + d]);   // prefetch before write
      float a = fmaf(w0, w4.x, bb);
      a = fmaf(w1, w4.y, a);
      a = fmaf(w2, w4.z, a);
      a = fmaf(w3, w4.w, a);
      float s = a * sigm(a);
      xiD[l * XI_LD + d] = f2bf(s);      // xc overwrites xi
      w0 = w1; w1 = w2; w2 = w3;
    }
  }
  __syncthreads();

  // ---- P3: x_proj MFMA (6 wave-tiles over 4 waves) -> dt/bc f32 in LDS ----
  for (int tt = wv; tt < 6; tt += 4) {
    const int mt = tt / 3, nt = tt - mt * 3;
    const u16* xph = ws + (dir ? WS_B_XP_HI : WS_F_XP_HI);
    const u16* xpl = ws + (dir ? WS_B_XP_LO : WS_F_XP_LO);
    const int raa = (mt * 16 + lr < LSEQ) ? (mt * 16 + lr) : (LSEQ - 1);
    f32x4 acc = f32x4{0.f, 0.f, 0.f, 0.f};
    const u16* bh_p = xph + (nt * 16 + lr) * 256 + lg * 8;
    const u16* bl_p = xpl + (nt * 16 + lr) * 256 + lg * 8;
#pragma unroll
    for (int kt = 0; kt < 8; kt += 2) {    // grouped loads -> deeper VMEM pipe
      bf16x8 a0  = *(const bf16x8*)&xiD[raa * XI_LD + kt * 32 + lg * 8];
      bf16x8 a1  = *(const bf16x8*)&xiD[raa * XI_LD + (kt + 1) * 32 + lg * 8];
      bf16x8 bh0 = *(const bf16x8*)(bh_p + kt * 32);
      bf16x8 bl0 = *(const bf16x8*)(bl_p + kt * 32);
      bf16x8 bh1 = *(const bf16x8*)(bh_p + (kt + 1) * 32);
      bf16x8 bl1 = *(const bf16x8*)(bl_p + (kt + 1) * 32);
      acc = __builtin_amdgcn_mfma_f32_16x16x32_bf16(a0, bh0, acc, 0, 0, 0);
      acc = __builtin_amdgcn_mfma_f32_16x16x32_bf16(a0, bl0, acc, 0, 0, 0);
      acc = __builtin_amdgcn_mfma_f32_16x16x32_bf16(a1, bh1, acc, 0, 0, 0);
      acc = __builtin_amdgcn_mfma_f32_16x16x32_bf16(a1, bl1, acc, 0, 0, 0);
    }
    const int col = nt * 16 + lr;
    float* dtD = (float*)pool;           // f32[22][8]  at u16 offset 0
    float* bcD = ((float*)pool) + 176;   // f32[22][32] at u16 offset 352
#pragma unroll
    for (int j = 0; j < 4; ++j) {
      int row = mt * 16 + lg * 4 + j;
      if (row < LSEQ) {
        if (col < 8) dtD[row * 8 + col] = acc[j];
        else if (col < 40) bcD[row * 32 + (col - 8)] = acc[j];
      }
    }
  }
  __syncthreads();

  // ---- P4: pipelined softplus(dt) + selective scan + D-skip + precomputed gate ----
  {
    const int d = tid;
    const float* dtw  = dir ? b_dt_w : f_dt_w;
    const float* dtb  = dir ? b_dt_b : f_dt_b;
    const float* Alog = dir ? b_Alog : f_Alog;
    const float* Dp   = dir ? b_D : f_D;
    const float* dtD  = (const float*)pool;
    const float* bcD  = ((const float*)pool) + 176;
    const u16* gD  = zD;     // g = silu(z), bf16 (from P1)
    const u16* xcD = xiD;    // xc (from P2)

    float4 dw0 = *(const float4*)(dtw + d * 8);
    float4 dw1 = *(const float4*)(dtw + d * 8 + 4);
    const float dtbv = dtb[d];
    float Av2[16];           // -exp(Alog) * log2(e): dA = exp2(dtv * Av2)
#pragma unroll
    for (int s4 = 0; s4 < 4; ++s4) {
      float4 a = *(const float4*)(Alog + d * 16 + s4 * 4);
      Av2[s4 * 4 + 0] = -__expf(a.x) * 1.44269504f;
      Av2[s4 * 4 + 1] = -__expf(a.y) * 1.44269504f;
      Av2[s4 * 4 + 2] = -__expf(a.z) * 1.44269504f;
      Av2[s4 * 4 + 3] = -__expf(a.w) * 1.44269504f;
    }
    const float Dd = Dp[d];
    u16* wsY = ws + WS_Y + (size_t)b * 11264 + dir * 5632;
    const int r0 = dir ? (LSEQ - 1) : 0;
    const int rstep = dir ? -1 : 1;

    auto softp8 = [&](float4 q0, float4 q1) -> float {
      float sdt = dtbv;
      sdt = fmaf(q0.x, dw0.x, sdt); sdt = fmaf(q0.y, dw0.y, sdt);
      sdt = fmaf(q0.z, dw0.z, sdt); sdt = fmaf(q0.w, dw0.w, sdt);
      sdt = fmaf(q1.x, dw1.x, sdt); sdt = fmaf(q1.y, dw1.y, sdt);
      sdt = fmaf(q1.z, dw1.z, sdt); sdt = fmaf(q1.w, dw1.w, sdt);
      return (sdt > 20.f) ? sdt : __logf(1.f + __expf(sdt));
    };

    float h[16];
#pragma unroll
    for (int s = 0; s < 16; ++s) h[s] = 0.f;

#define SC(s, bv, cv) { float dA = __builtin_amdgcn_exp2f(dtv * Av2[s]); \
      h[s] = fmaf(dA, h[s], du * (bv)); \
      acc = fmaf(h[s], (cv), acc); }
    auto STEP = [&](int l, float dtv) {
      float u = bf2f(xcD[l * XI_LD + d]);
      float g = bf2f(gD[l * XI_LD + d]);
      float4 b0 = *(const float4*)(bcD + l * 32);
      float4 b1 = *(const float4*)(bcD + l * 32 + 4);
      float4 b2 = *(const float4*)(bcD + l * 32 + 8);
      float4 b3 = *(const float4*)(bcD + l * 32 + 12);
      float4 c0 = *(const float4*)(bcD + l * 32 + 16);
      float4 c1 = *(const float4*)(bcD + l * 32 + 20);
      float4 c2 = *(const float4*)(bcD + l * 32 + 24);
      float4 c3 = *(const float4*)(bcD + l * 32 + 28);
      float du = dtv * u;
      float acc = 0.f;
      SC(0, b0.x, c0.x) SC(1, b0.y, c0.y) SC(2, b0.z, c0.z) SC(3, b0.w, c0.w)
      SC(4, b1.x, c1.x) SC(5, b1.y, c1.y) SC(6, b1.z, c1.z) SC(7, b1.w, c1.w)
      SC(8, b2.x, c2.x) SC(9, b2.y, c2.y) SC(10, b2.z, c2.z) SC(11, b2.w, c2.w)
      SC(12, b3.x, c3.x) SC(13, b3.y, c3.y) SC(14, b3.z, c3.z) SC(15, b3.w, c3.w)
      float yo = fmaf(u, Dd, acc) * g;
      wsY[(r0 + rstep * l) * DI + d] = f2bf(yo);
    };
#undef SC

    // 2-step software pipeline: q rows fetched one pair ahead; softplus for
    // steps l+2/l+3 computed during steps l/l+1 (off the carried chain).
    float4 qa0 = *(const float4*)(dtD + 0);
    float4 qa1 = *(const float4*)(dtD + 4);
    float4 qb0 = *(const float4*)(dtD + 8);
    float4 qb1 = *(const float4*)(dtD + 12);
    float dtvA = softp8(qa0, qa1);
    float dtvB = softp8(qb0, qb1);

    for (int ll = 0; ll < LSEQ; ll += 2) {
      const int l2 = (ll + 2 < LSEQ) ? (ll + 2) : (LSEQ - 2);   // clamp: tail reads valid rows, results unused
      qa0 = *(const float4*)(dtD + l2 * 8);
      qa1 = *(const float4*)(dtD + l2 * 8 + 4);
      qb0 = *(const float4*)(dtD + l2 * 8 + 8);
      qb1 = *(const float4*)(dtD + l2 * 8 + 12);
      STEP(ll, dtvA);
      STEP(ll + 1, dtvB);
      dtvA = softp8(qa0, qa1);
      dtvB = softp8(qb0, qb1);
    }
  }
}

// ============ K2: per (nm, t) — folded out_proj/fuse + LayerNorm ============
__global__ __launch_bounds__(256, 6) void fold_ln_kernel(
    const float* __restrict__ ln_w, const float* __restrict__ ln_b,
    const u16* __restrict__ ws, float* __restrict__ out)
{
  __shared__ __align__(16) u16 pool[K2_N];

  const int tid = threadIdx.x;
  const int wv = tid >> 6, ln = tid & 63, lr = ln & 15, lg = ln >> 4;
  const int b = blockIdx.x;
  const int nm = b / TDIM, t = b - nm * TDIM;
  const size_t base = (size_t)nm * CD * (TDIM * LSEQ) + (size_t)t * LSEQ;
  const u16* wsY = ws + WS_Y + (size_t)b * 11264;

  // ---- stage y_f, y_b (both already in sequence order) ----
  for (int idx = tid; idx < 2 * LSEQ * 32; idx += 256) {   // 1408 x bf16x8
    int dirc = idx / 704, r = idx - dirc * 704;
    int l = r >> 5, ch = (r & 31) * 8;
    *(bf16x8*)&pool[dirc * 5808 + l * XI_LD + ch] =
        *(const bf16x8*)(wsY + dirc * 5632 + l * 256 + ch);
  }
  __syncthreads();

  const int ra0 = (lr < LSEQ) ? lr : (LSEQ - 1);
  const int ra1 = (16 + lr < LSEQ) ? (16 + lr) : (LSEQ - 1);

  // ---- y2 = y_f @ Wf.T + y_b @ Wb.T ----
  f32x4 acc[2][2];
#pragma unroll
  for (int m = 0; m < 2; ++m)
#pragma unroll
    for (int n = 0; n < 2; ++n) acc[m][n] = f32x4{0.f, 0.f, 0.f, 0.f};
#pragma unroll
  for (int dirc = 0; dirc < 2; ++dirc) {
    const u16* wp = ws + (dirc ? WS_B_OUT : WS_F_OUT);
    const u16* yD = pool + dirc * 5808;
#pragma unroll
    for (int kt = 0; kt < 8; ++kt) {
      bf16x8 a0 = *(const bf16x8*)&yD[ra0 * XI_LD + kt * 32 + lg * 8];
      bf16x8 a1 = *(const bf16x8*)&yD[ra1 * XI_LD + kt * 32 + lg * 8];
#pragma unroll
      for (int n = 0; n < 2; ++n) {
        bf16x8 bw = *(const bf16x8*)(wp + (wv * 32 + n * 16 + lr) * 256 + kt * 32 + lg * 8);
        acc[0][n] = __builtin_amdgcn_mfma_f32_16x16x32_bf16(a0, bw, acc[0][n], 0, 0, 0);
        acc[1][n] = __builtin_amdgcn_mfma_f32_16x16x32_bf16(a1, bw, acc[1][n], 0, 0, 0);
      }
    }
  }
  __syncthreads();   // all waves done reading yf/yb before overlay write

  float* y2 = (float*)pool;   // [22][132], overlays yf
#pragma unroll
  for (int m = 0; m < 2; ++m)
#pragma unroll
    for (int n = 0; n < 2; ++n)
#pragma unroll
      for (int j = 0; j < 4; ++j) {
        int row = 16 * m + lg * 4 + j;
        if (row < LSEQ) y2[row * Y2_LD + wv * 32 + n * 16 + lr] = acc[m][n][j];
      }
  __syncthreads();

  // ---- LayerNorm stats (one wave per row) ----
  float* mu_s = (float*)(pool + 5808);   // overlays yb
  float* rs_s = mu_s + LSEQ;
  for (int l = wv; l < LSEQ; l += 4) {
    float v1 = y2[l * Y2_LD + ln];
    float v2 = y2[l * Y2_LD + 64 + ln];
    float s = v1 + v2;
    float sq = v1 * v1 + v2 * v2;
#pragma unroll
    for (int m = 1; m < 64; m <<= 1) {
      s  += __shfl_xor(s, m, 64);
      sq += __shfl_xor(sq, m, 64);
    }
    if (ln == 0) {
      float mu = s * (1.0f / 128.0f);
      float var = sq * (1.0f / 128.0f) - mu * mu;
      mu_s[l] = mu;
      rs_s[l] = rsqrtf(var + 1e-5f);
    }
  }
  __syncthreads();

  // ---- normalize + transposed store ----
  for (int idx = tid; idx < LSEQ * CD; idx += 256) {
    int c = idx / LSEQ, v = idx - c * LSEQ;
    float yv = y2[v * Y2_LD + c];
    float o = (yv - mu_s[v]) * rs_s[v] * ln_w[c] + ln_b[c];
    out[base + (size_t)c * (TDIM * LSEQ) + v] = o;
  }
}

}  // namespace

extern "C" void kernel_launch(void* const* d_in, const int* in_sizes, int n_in,
                              void* d_out, int out_size, void* d_ws, size_t ws_size,
                              hipStream_t stream) {
  (void)in_sizes; (void)n_in; (void)ws_size; (void)out_size;
  const float* p[22];
  for (int i = 0; i < 22; ++i) p[i] = (const float*)d_in[i];
  u16* ws = (u16*)d_ws;
  prep_weights<<<dim3((WS_TOTAL + 255) / 256), dim3(256), 0, stream>>>(
      p[1], p[10], p[4], p[13], ws);
  prep_fold<<<dim3(256), dim3(256), 0, stream>>>(p[9], p[18], p[19], ws);
  mamba_scan_kernel<<<dim3(32 * 64 * 2), dim3(256), 0, stream>>>(
      p[0],
      p[2], p[3], p[5], p[6], p[7], p[8],
      p[11], p[12], p[14], p[15], p[16], p[17],
      ws);
  fold_ln_kernel<<<dim3(32 * 64), dim3(256), 0, stream>>>(
      p[20], p[21], ws, (float*)d_out);
}